// Round 1
// 20735.699 us; speedup vs baseline: 1.8639x; 1.8639x over previous
//
#include <hip/hip_runtime.h>
#include <math.h>

#define B_   128
#define T_   256
#define IN_  512
#define C_   2048
#define N_   256
#define M_   128
#define OUT_ 512
#define PR   134          // M_+6
#define PWW  390          // 3M+6
#define PTOT 1036         // PR + PWW + OUT_
#define COLP 1152         // padded P columns (9 tiles of 128)
#define ZP   16           // split-K partials for GEMM2
#define EPSF 1e-8f

__device__ __forceinline__ float softplusf(float x) { return (x > 20.f) ? x : log1pf(expf(x)); }
__device__ __forceinline__ float sigmoidf(float x) { return 1.f / (1.f + expf(-x)); }

// ---------------- init: state ----------------
__global__ __launch_bounds__(256) void init_state(
    float* __restrict__ mem, float* __restrict__ w_r, float* __restrict__ w_w,
    float* __restrict__ r,
    const float* __restrict__ mem_init, const float* __restrict__ read_init)
{
    int i0 = blockIdx.x * blockDim.x + threadIdx.x;
    int stride = gridDim.x * blockDim.x;
    for (int i = i0; i < B_ * N_ * M_; i += stride)
        mem[i] = mem_init[i & (N_ * M_ - 1)];
    for (int i = i0; i < B_ * N_; i += stride) { w_r[i] = 1.f / N_; w_w[i] = 1.f / N_; }
    for (int i = i0; i < B_ * M_; i += stride) r[i] = read_init[i & (M_ - 1)];
}

// ---------------- chunk precompute: Xc[tl*B+b][c] = x[b,t0+tl,:] @ Wc_x ----------------
// grid (16, CH); tile 128x128, 8x8/thread, K=512
__global__ __launch_bounds__(256) void gemm_xc(
    const float* __restrict__ x, const float* __restrict__ Wc,
    float* __restrict__ Xc, int t0)
{
    __shared__ __align__(16) float As[16][132];
    __shared__ __align__(16) float Bs[16][132];
    int col0 = blockIdx.x * 128;
    int row0 = blockIdx.y * 128;
    int tid = threadIdx.x, tx = tid & 15, ty = tid >> 4;
    float acc[8][8];
#pragma unroll
    for (int i = 0; i < 8; i++)
#pragma unroll
        for (int j = 0; j < 8; j++) acc[i][j] = 0.f;

    for (int k0 = 0; k0 < IN_; k0 += 16) {
#pragma unroll
        for (int l = 0; l < 8; l++) {
            int e = tid + l * 256;
            int rr = e >> 4, kk = e & 15;
            int rg = row0 + rr;
            int tl = rg >> 7, bb = rg & 127;
            As[kk][rr] = x[((size_t)bb * T_ + t0 + tl) * IN_ + k0 + kk];
        }
#pragma unroll
        for (int l = 0; l < 8; l++) {
            int e = tid + l * 256;
            int kk = e >> 7, cc = e & 127;
            Bs[kk][cc] = Wc[(size_t)(M_ + k0 + kk) * C_ + col0 + cc];
        }
        __syncthreads();
#pragma unroll
        for (int kk = 0; kk < 16; kk++) {
            float4 alo = *(const float4*)&As[kk][ty * 4];
            float4 ahi = *(const float4*)&As[kk][64 + ty * 4];
            float4 blo = *(const float4*)&Bs[kk][tx * 4];
            float4 bhi = *(const float4*)&Bs[kk][64 + tx * 4];
            float av[8] = {alo.x, alo.y, alo.z, alo.w, ahi.x, ahi.y, ahi.z, ahi.w};
            float bv[8] = {blo.x, blo.y, blo.z, blo.w, bhi.x, bhi.y, bhi.z, bhi.w};
#pragma unroll
            for (int i = 0; i < 8; i++)
#pragma unroll
                for (int j = 0; j < 8; j++) acc[i][j] += av[i] * bv[j];
        }
        __syncthreads();
    }
#pragma unroll
    for (int i = 0; i < 8; i++) {
        int gr = row0 + ((i < 4) ? (ty * 4 + i) : (64 + ty * 4 + i - 4));
        float* dst = Xc + (size_t)gr * C_ + col0;
        *(float4*)&dst[tx * 4]      = make_float4(acc[i][0], acc[i][1], acc[i][2], acc[i][3]);
        *(float4*)&dst[64 + tx * 4] = make_float4(acc[i][4], acc[i][5], acc[i][6], acc[i][7]);
    }
}

// ---------------- per-step: h = tanh(r @ Wc_r + Xc_t + bc), K=128 ----------------
// grid (64, 4); tile 32x32, 2x2/thread
__global__ __launch_bounds__(256) void gemm_h(
    const float* __restrict__ r, const float* __restrict__ Wc,
    const float* __restrict__ XcT, const float* __restrict__ bc,
    float* __restrict__ h)
{
    __shared__ __align__(16) float As[16][36];
    __shared__ __align__(16) float Bs[16][36];
    int col0 = blockIdx.x * 32;
    int row0 = blockIdx.y * 32;
    int tid = threadIdx.x, tx = tid & 15, ty = tid >> 4;
    float acc[2][2] = {{0.f, 0.f}, {0.f, 0.f}};

    for (int k0 = 0; k0 < M_; k0 += 16) {
#pragma unroll
        for (int l = 0; l < 2; l++) {
            int e = tid + l * 256;
            As[e & 15][e >> 4] = r[(size_t)(row0 + (e >> 4)) * M_ + k0 + (e & 15)];
            Bs[e >> 5][e & 31] = Wc[(size_t)(k0 + (e >> 5)) * C_ + col0 + (e & 31)];
        }
        __syncthreads();
#pragma unroll
        for (int kk = 0; kk < 16; kk++) {
            float2 a2 = *(const float2*)&As[kk][ty * 2];
            float2 b2 = *(const float2*)&Bs[kk][tx * 2];
            acc[0][0] += a2.x * b2.x; acc[0][1] += a2.x * b2.y;
            acc[1][0] += a2.y * b2.x; acc[1][1] += a2.y * b2.y;
        }
        __syncthreads();
    }
#pragma unroll
    for (int i = 0; i < 2; i++) {
        int gr = row0 + ty * 2 + i;
        int gc = col0 + tx * 2;
        float2 xc2 = *(const float2*)&XcT[(size_t)gr * C_ + gc];
        float2 bc2 = *(const float2*)&bc[gc];
        float2 o;
        o.x = tanhf(acc[i][0] + xc2.x + bc2.x);
        o.y = tanhf(acc[i][1] + xc2.y + bc2.y);
        *(float2*)&h[(size_t)gr * C_ + gc] = o;
    }
}

// ---------------- per-step: Ppart[z] = h @ [Wr|Ww|Wout], split-K=16 ----------------
// grid (9, 1, 16); tile 128x128, 8x8/thread, KS=128
__global__ __launch_bounds__(256) void gemm_p(
    const float* __restrict__ h,
    const float* __restrict__ Wr, const float* __restrict__ Ww, const float* __restrict__ Wout,
    float* __restrict__ Ppart)
{
    __shared__ __align__(16) float As[16][132];
    __shared__ __align__(16) float Bs[16][132];
    const int KS = C_ / ZP;   // 128
    int col0 = blockIdx.x * 128;
    int z = blockIdx.z;
    int tid = threadIdx.x, tx = tid & 15, ty = tid >> 4;
    float acc[8][8];
#pragma unroll
    for (int i = 0; i < 8; i++)
#pragma unroll
        for (int j = 0; j < 8; j++) acc[i][j] = 0.f;

    int kbase = z * KS;
    for (int k0 = kbase; k0 < kbase + KS; k0 += 16) {
#pragma unroll
        for (int l = 0; l < 8; l++) {
            int e = tid + l * 256;
            int rr = e >> 4, kk = e & 15;
            As[kk][rr] = h[(size_t)rr * C_ + k0 + kk];
        }
#pragma unroll
        for (int l = 0; l < 8; l++) {
            int e = tid + l * 256;
            int kk = e >> 7, cc = e & 127;
            int gc = col0 + cc, gk = k0 + kk;
            float v = 0.f;
            if (gc < PR)            v = Wr[(size_t)gk * PR + gc];
            else if (gc < PR + PWW) v = Ww[(size_t)gk * PWW + (gc - PR)];
            else if (gc < PTOT)     v = Wout[(size_t)gk * OUT_ + (gc - PR - PWW)];
            Bs[kk][cc] = v;
        }
        __syncthreads();
#pragma unroll
        for (int kk = 0; kk < 16; kk++) {
            float4 alo = *(const float4*)&As[kk][ty * 4];
            float4 ahi = *(const float4*)&As[kk][64 + ty * 4];
            float4 blo = *(const float4*)&Bs[kk][tx * 4];
            float4 bhi = *(const float4*)&Bs[kk][64 + tx * 4];
            float av[8] = {alo.x, alo.y, alo.z, alo.w, ahi.x, ahi.y, ahi.z, ahi.w};
            float bv[8] = {blo.x, blo.y, blo.z, blo.w, bhi.x, bhi.y, bhi.z, bhi.w};
#pragma unroll
            for (int i = 0; i < 8; i++)
#pragma unroll
                for (int j = 0; j < 8; j++) acc[i][j] += av[i] * bv[j];
        }
        __syncthreads();
    }
    float* Pp = Ppart + (size_t)z * B_ * COLP;
#pragma unroll
    for (int i = 0; i < 8; i++) {
        int gr = (i < 4) ? (ty * 4 + i) : (64 + ty * 4 + i - 4);
        float* dst = Pp + (size_t)gr * COLP + col0;
        *(float4*)&dst[tx * 4]      = make_float4(acc[i][0], acc[i][1], acc[i][2], acc[i][3]);
        *(float4*)&dst[64 + tx * 4] = make_float4(acc[i][4], acc[i][5], acc[i][6], acc[i][7]);
    }
}

// ---------------- fused addressing: one block per (batch, head) ----------------
struct __align__(16) SM {
    float p[400];      // staged head params (134 read / 390 write), reused as scratch
    float wsh[N_];
    float ea[2 * M_];
    float red[8];      // two 4-entry reduction slots
};

__device__ __forceinline__ float redSum(SM& sm, float v, int slot) {
#pragma unroll
    for (int off = 32; off; off >>= 1) v += __shfl_xor(v, off, 64);
    if ((threadIdx.x & 63) == 0) sm.red[slot * 4 + (threadIdx.x >> 6)] = v;
    __syncthreads();
    return (sm.red[slot * 4] + sm.red[slot * 4 + 1]) + (sm.red[slot * 4 + 2] + sm.red[slot * 4 + 3]);
}
__device__ __forceinline__ float redMax(SM& sm, float v, int slot) {
#pragma unroll
    for (int off = 32; off; off >>= 1) v = fmaxf(v, __shfl_xor(v, off, 64));
    if ((threadIdx.x & 63) == 0) sm.red[slot * 4 + (threadIdx.x >> 6)] = v;
    __syncthreads();
    return fmaxf(fmaxf(sm.red[slot * 4], sm.red[slot * 4 + 1]),
                 fmaxf(sm.red[slot * 4 + 2], sm.red[slot * 4 + 3]));
}

// addressing math over sm.p[0..134); leaves final w in sm.wsh and wglob
__device__ __forceinline__ void compute_w(
    SM& sm, const float* __restrict__ mem, float* __restrict__ wglob, int b)
{
    int tid = threadIdx.x;
    float kv = (tid < M_) ? sm.p[tid] : 0.f;
    float knorm = sqrtf(redSum(sm, kv * kv, 0));
    // scalars computed redundantly by every thread (LDS broadcast reads)
    float beta = softplusf(sm.p[M_]);
    float g    = sigmoidf(sm.p[M_ + 1]);
    float a0 = sm.p[M_ + 2], a1 = sm.p[M_ + 3], a2 = sm.p[M_ + 4];
    float mx3 = fmaxf(a0, fmaxf(a1, a2));
    float e0 = expf(a0 - mx3), e1 = expf(a1 - mx3), e2 = expf(a2 - mx3);
    float inv3 = 1.f / (e0 + e1 + e2);
    float s0 = e0 * inv3, s1 = e1 * inv3, s2 = e2 * inv3;
    float gamma = 1.f + softplusf(sm.p[M_ + 5]);

    // cosine similarity: one memory row per thread
    const float* mrow = mem + ((size_t)b * N_ + tid) * M_;
    float dot = 0.f, nrm = 0.f;
#pragma unroll 8
    for (int m = 0; m < M_; m += 4) {
        float4 v = *(const float4*)&mrow[m];
        float4 kk = *(const float4*)&sm.p[m];
        dot += v.x * kk.x + v.y * kk.y + v.z * kk.z + v.w * kk.w;
        nrm += v.x * v.x + v.y * v.y + v.z * v.z + v.w * v.w;
    }
    float sim = dot / (knorm * sqrtf(nrm) + EPSF);
    float zz = beta * sim;
    float mx = redMax(sm, zz, 1);
    float ez = expf(zz - mx);
    float wc = ez / redSum(sm, ez, 0);
    float wgv = g * wc + (1.f - g) * wglob[(size_t)b * N_ + tid];
    sm.wsh[tid] = wgv;
    __syncthreads();
    float wt = s0 * sm.wsh[(tid + 1) & (N_ - 1)]
             + s1 * wgv
             + s2 * sm.wsh[(tid + N_ - 1) & (N_ - 1)];
    float wp = powf(wt + EPSF, gamma);
    float wfin = wp / redSum(sm, wp, 1);   // internal barrier covers wsh reads above
    wglob[(size_t)b * N_ + tid] = wfin;
    sm.wsh[tid] = wfin;
    __syncthreads();
}

// grid (128, 2) split mode (memB != memA), or (128, 1) seq mode (in-place)
__global__ __launch_bounds__(256) void addr_fused(
    const float* __restrict__ Ppart,
    const float* __restrict__ br, const float* __restrict__ bw, const float* __restrict__ bout,
    const float* __restrict__ memA, float* __restrict__ memB,
    float* __restrict__ w_r, float* __restrict__ w_w,
    float* __restrict__ r_out, float* __restrict__ out, int t, int seq)
{
    __shared__ SM sm;
    int b = blockIdx.x, tid = threadIdx.x;
    bool doRead  = seq || (blockIdx.y == 0);
    bool doWrite = seq || (blockIdx.y == 1);
    const float* Pb = Ppart + (size_t)b * COLP;

    if (doRead) {
        for (int c = tid; c < PR; c += 256) {
            float v = br[c];
#pragma unroll
            for (int z = 0; z < ZP; z++) v += Pb[(size_t)z * B_ * COLP + c];
            sm.p[c] = v;
        }
        __syncthreads();
        compute_w(sm, memA, w_r, b);
        // r_new from OLD mem
        {
            int m = tid & (M_ - 1), half = tid >> 7;
            const float* mb = memA + (size_t)b * N_ * M_;
            float acc = 0.f;
            int n0 = half * 128;
#pragma unroll 4
            for (int n = n0; n < n0 + 128; n++) acc += sm.wsh[n] * mb[(size_t)n * M_ + m];
            sm.p[tid] = acc;   // safe: compute_w's trailing barrier passed all p-reads
            __syncthreads();
            if (tid < M_) r_out[(size_t)b * M_ + tid] = sm.p[tid] + sm.p[tid + 128];
        }
        // out = P cols [524, 1036)
        for (int j = tid; j < OUT_; j += 256) {
            float v = bout[j];
#pragma unroll
            for (int z = 0; z < ZP; z++) v += Pb[(size_t)z * B_ * COLP + PR + PWW + j];
            out[((size_t)b * T_ + t) * OUT_ + j] = v;
        }
    }
    if (doWrite) {
        __syncthreads();   // seq mode: drain read-phase LDS use before re-staging
        for (int c = tid; c < PWW; c += 256) {
            float v = bw[c];
#pragma unroll
            for (int z = 0; z < ZP; z++) v += Pb[(size_t)z * B_ * COLP + PR + c];
            sm.p[c] = v;
        }
        __syncthreads();
        compute_w(sm, memA, w_w, b);
        if (tid < M_) {
            sm.ea[tid]       = sigmoidf(sm.p[PR + tid]);         // e
            sm.ea[M_ + tid]  = tanhf(sm.p[PR + M_ + tid]);       // a
        }
        __syncthreads();
        const float4* ma4 = (const float4*)(memA + (size_t)b * N_ * M_);
        float4* mb4 = (float4*)(memB + (size_t)b * N_ * M_);
        for (int idx = tid; idx < N_ * M_ / 4; idx += 256) {
            int n = idx >> 5;
            int mq = (idx & 31) << 2;
            float wv = sm.wsh[n];
            float4 v = ma4[idx];
            float4 e4 = *(const float4*)&sm.ea[mq];
            float4 a4 = *(const float4*)&sm.ea[M_ + mq];
            v.x = v.x * (1.f - wv * e4.x) + wv * a4.x;
            v.y = v.y * (1.f - wv * e4.y) + wv * a4.y;
            v.z = v.z * (1.f - wv * e4.z) + wv * a4.z;
            v.w = v.w * (1.f - wv * e4.w) + wv * a4.w;
            mb4[idx] = v;
        }
    }
}

// ---------------- launch ----------------
static const float* by_size(void* const* d_in, const int* in_sizes, int n_in,
                            long long want, int fallback)
{
    for (int i = 0; i < n_in; i++)
        if ((long long)in_sizes[i] == want) return (const float*)d_in[i];
    return (const float*)d_in[fallback];
}

extern "C" void kernel_launch(void* const* d_in, const int* in_sizes, int n_in,
                              void* d_out, int out_size, void* d_ws, size_t ws_size,
                              hipStream_t stream)
{
    const float* x         = by_size(d_in, in_sizes, n_in, (long long)B_ * T_ * IN_, 0);
    const float* Wc        = by_size(d_in, in_sizes, n_in, (long long)(M_ + IN_) * C_, 1);
    const float* bc        = by_size(d_in, in_sizes, n_in, C_, 2);
    const float* Wout      = by_size(d_in, in_sizes, n_in, (long long)C_ * OUT_, 3);
    const float* bout      = by_size(d_in, in_sizes, n_in, OUT_, 4);
    const float* Wr        = by_size(d_in, in_sizes, n_in, (long long)C_ * PR, 5);
    const float* br        = by_size(d_in, in_sizes, n_in, PR, 6);
    const float* Ww        = by_size(d_in, in_sizes, n_in, (long long)C_ * PWW, 7);
    const float* bw        = by_size(d_in, in_sizes, n_in, PWW, 8);
    const float* mem_init  = by_size(d_in, in_sizes, n_in, N_ * M_, 9);
    const float* read_init = by_size(d_in, in_sizes, n_in, M_, 10);
    float* out = (float*)d_out;

    auto pad = [](size_t s) { return (s + 255) & ~(size_t)255; };
    const size_t SZ_MEM = (size_t)B_ * N_ * M_ * sizeof(float);
    const size_t SZ_R   = (size_t)B_ * M_ * sizeof(float);
    const size_t SZ_W   = (size_t)B_ * N_ * sizeof(float);
    const size_t SZ_H   = (size_t)B_ * C_ * sizeof(float);
    const size_t SZ_PP  = (size_t)ZP * B_ * COLP * sizeof(float);
    const size_t SZ_XC1 = (size_t)B_ * C_ * sizeof(float);   // one timestep of Xc

    size_t fixedsz = pad(SZ_MEM) + pad(SZ_R) + 2 * pad(SZ_W) + pad(SZ_H) + pad(SZ_PP);
    int split = (fixedsz + pad(SZ_MEM) + pad(SZ_XC1) <= ws_size) ? 1 : 0;
    size_t used = fixedsz + (split ? pad(SZ_MEM) : 0);
    size_t rem = (ws_size > used) ? (ws_size - used) : 0;
    int CH = 1;
    while (CH < T_ && pad((size_t)(CH * 2) * SZ_XC1) <= rem) CH <<= 1;

    char* p = (char*)d_ws;
    auto alloc = [&](size_t bytes) -> void* {
        void* q = (void*)p;
        p += pad(bytes);
        return q;
    };
    float* memA = (float*)alloc(SZ_MEM);
    float* r    = (float*)alloc(SZ_R);
    float* w_r  = (float*)alloc(SZ_W);
    float* w_w  = (float*)alloc(SZ_W);
    float* h    = (float*)alloc(SZ_H);
    float* Pp   = (float*)alloc(SZ_PP);
    float* memB = split ? (float*)alloc(SZ_MEM) : memA;
    float* Xc   = (float*)alloc((size_t)CH * SZ_XC1);

    init_state<<<1024, 256, 0, stream>>>(memA, w_r, w_w, r, mem_init, read_init);

    float* ma = memA;
    float* mb = memB;
    for (int t = 0; t < T_; t++) {
        if ((t & (CH - 1)) == 0)
            gemm_xc<<<dim3(C_ / 128, CH), 256, 0, stream>>>(x, Wc, Xc, t);
        gemm_h<<<dim3(C_ / 32, B_ / 32), 256, 0, stream>>>(
            r, Wc, Xc + (size_t)(t & (CH - 1)) * B_ * C_, bc, h);
        gemm_p<<<dim3(9, 1, ZP), 256, 0, stream>>>(h, Wr, Ww, Wout, Pp);
        addr_fused<<<dim3(B_, split ? 2 : 1), 256, 0, stream>>>(
            Pp, br, bw, bout, ma, mb, w_r, w_w, r, out, t, split ? 0 : 1);
        if (split) { float* tmp = ma; ma = mb; mb = tmp; }
    }
}